// Round 4
// baseline (174.606 us; speedup 1.0000x reference)
//
#include <hip/hip_runtime.h>
#include <hip/hip_bf16.h>

// Problem constants
#define BQ   8
#define HW   16384        // 128*128
#define CIN  64
#define C3   192
#define KPB  64           // blocks per batch (512 blocks total)

typedef __attribute__((ext_vector_type(8))) short short8;   // 8 bf16 (4 VGPR)
typedef __attribute__((ext_vector_type(4))) float f32x4;    // MFMA accumulator

__device__ __forceinline__ ushort f2bf(float f) {
    // round-to-nearest-even fp32 -> bf16 (inputs are finite normals)
    uint u = __float_as_uint(f);
    u += 0x7fffu + ((u >> 16) & 1u);
    return (ushort)(u >> 16);
}

// ---------------------------------------------------------------------------
// K1: read fp32 inputs once, emit bf16 xws[pix][k'=t*64+c] + channel sums.
//     partials[bid][c3], c3 = 3*c + t  (matches SE gate indexing).
// ---------------------------------------------------------------------------
__global__ __launch_bounds__(256) void k_prep(const float* __restrict__ t1,
                                              const float* __restrict__ t2,
                                              const float* __restrict__ t3,
                                              ushort* __restrict__ xws,
                                              float* __restrict__ partials) {
    const int bid  = blockIdx.x;
    const int b    = bid >> 6;
    const int kblk = bid & 63;
    const int tid  = threadIdx.x;
    const int lane = tid & 63, wave = tid >> 6;
    const int l16  = lane & 15;

    const size_t pixbase = (size_t)b * HW + (size_t)kblk * 256;  // 256 px/block
    float acc[3][4] = {{0.f,0.f,0.f,0.f},{0.f,0.f,0.f,0.f},{0.f,0.f,0.f,0.f}};

#pragma unroll
    for (int j = 0; j < 4; ++j) {                 // 64-pixel sub-tiles
        const size_t cb = (pixbase + (size_t)j * 64) * CIN;
        ushort* xw = xws + (pixbase + (size_t)j * 64) * C3;
#pragma unroll
        for (int t = 0; t < 3; ++t) {
            const float* base = (t == 0) ? t1 : (t == 1) ? t2 : t3;
            const float4* s = (const float4*)(base + cb);
#pragma unroll
            for (int i = 0; i < 4; ++i) {
                const int idx = i * 256 + tid;    // float4 idx; c=(idx&15)*4 fixed/lane
                float4 v = s[idx];
                acc[t][0] += v.x; acc[t][1] += v.y;
                acc[t][2] += v.z; acc[t][3] += v.w;
                const int pix = idx >> 4, c = (idx & 15) * 4;
                ushort4 pk;
                pk.x = f2bf(v.x); pk.y = f2bf(v.y);
                pk.z = f2bf(v.z); pk.w = f2bf(v.w);
                *(ushort4*)&xw[pix * C3 + t * CIN + c] = pk;   // 8B coalesced
            }
        }
    }
    // lanes l, l+16, l+32, l+48 share the same channel group -> butterfly
#pragma unroll
    for (int t = 0; t < 3; ++t)
#pragma unroll
        for (int jj = 0; jj < 4; ++jj) {
            float v = acc[t][jj];
            v += __shfl_xor(v, 16);
            v += __shfl_xor(v, 32);
            acc[t][jj] = v;
        }
    __shared__ float red[4][C3];
    if (lane < 16) {
#pragma unroll
        for (int t = 0; t < 3; ++t)
#pragma unroll
            for (int jj = 0; jj < 4; ++jj)
                red[wave][3 * (l16 * 4 + jj) + t] = acc[t][jj];
    }
    __syncthreads();
    if (tid < C3) {
        float v = red[0][tid] + red[1][tid] + red[2][tid] + red[3][tid];
        partials[(size_t)bid * C3 + tid] = v;
    }
}

// ---------------------------------------------------------------------------
// K2: finish mean, SE dense layers (fp32), emit folded bf16 weights
//     wbT[b][f][k'] with k' = t*64 + c
// ---------------------------------------------------------------------------
__global__ __launch_bounds__(256) void k_se(const float* __restrict__ partials,
                                            const float* __restrict__ w_se1,
                                            const float* __restrict__ w_se2,
                                            const float* __restrict__ w_conv,
                                            ushort* __restrict__ wbT) {
    const int b = blockIdx.x, tid = threadIdx.x;
    __shared__ float s_lds[C3];
    __shared__ float h_lds[12];
    __shared__ float sig_lds[C3];

    if (tid < C3) {
        float s = 0.f;
        const float* p = partials + (size_t)b * KPB * C3 + tid;
        for (int k = 0; k < KPB; ++k) s += p[k * C3];
        s_lds[tid] = s * (1.f / 16384.f);
    }
    __syncthreads();
    if (tid < 12) {
        float h = 0.f;
        for (int j = 0; j < C3; ++j) h += s_lds[j] * w_se1[j * 12 + tid];
        h_lds[tid] = fmaxf(h, 0.f);
    }
    __syncthreads();
    if (tid < C3) {
        float z = 0.f;
#pragma unroll
        for (int i = 0; i < 12; ++i) z += h_lds[i] * w_se2[i * C3 + tid];
        sig_lds[tid] = 1.f / (1.f + expf(-z));
    }
    __syncthreads();
    if (tid < C3) {
        const int c = tid & 63, t = tid >> 6;
        const int c3 = 3 * c + t;                 // original interleaved index
        const float g = sig_lds[c3];
        ushort* dst = wbT + (size_t)b * CIN * C3; // [64][192] bf16
        for (int f = 0; f < CIN; ++f)
            dst[f * C3 + tid] = f2bf(g * w_conv[c3 * CIN + f]);
    }
}

// ---------------------------------------------------------------------------
// K3: MFMA conv. A-fragments straight from global xws (L3-hot, perfect 64B
//     line utilization); only wt (25.6 KB) staged in LDS. One barrier total.
// ---------------------------------------------------------------------------
__global__ __launch_bounds__(256) void k_conv(const ushort* __restrict__ xws,
                                              const ushort* __restrict__ wbT,
                                              const float* __restrict__ b_conv,
                                              float* __restrict__ out) {
    __shared__ ushort wt[64 * 200];   // weights [64 f][192 k'] pad->200

    const int bid  = blockIdx.x;
    const int b    = bid >> 6;
    const int kblk = bid & 63;
    const int tid  = threadIdx.x;
    const int lane = tid & 63, wave = tid >> 6;
    const int l16  = lane & 15, lhi = lane >> 4;

    // stage per-batch folded weights once
    {
        const uint2* src = (const uint2*)(wbT + (size_t)b * CIN * C3);
#pragma unroll
        for (int i = 0; i < 12; ++i) {
            int ch  = i * 256 + tid;      // 0..3071 8-byte chunks (48 per row)
            int row = ch / 48, col8 = ch % 48;
            *(uint2*)&wt[row * 200 + col8 * 4] = src[ch];
        }
    }
    float bias[4];
#pragma unroll
    for (int ft = 0; ft < 4; ++ft) bias[ft] = b_conv[ft * 16 + l16];
    __syncthreads();

    const size_t pixbase = (size_t)b * HW + (size_t)kblk * 256;
#pragma unroll
    for (int j = 0; j < 4; ++j) {
        const size_t prow = pixbase + (size_t)j * 64 + wave * 16 + l16;
        const ushort* arow = xws + prow * C3;     // this lane's pixel row

        f32x4 a4[4];
#pragma unroll
        for (int ft = 0; ft < 4; ++ft) a4[ft] = (f32x4){0.f, 0.f, 0.f, 0.f};
#pragma unroll
        for (int kt = 0; kt < 6; ++kt) {
            short8 a = *(const short8*)&arow[kt * 32 + lhi * 8];
#pragma unroll
            for (int ft = 0; ft < 4; ++ft) {
                short8 bb = *(const short8*)&wt[(ft * 16 + l16) * 200 + kt * 32 + lhi * 8];
                a4[ft] = __builtin_amdgcn_mfma_f32_16x16x32_bf16(a, bb, a4[ft], 0, 0, 0);
            }
        }
        // D: col = l16 (f), row = lhi*4 + r (pixel)  [m89-verified layout]
        const size_t obase = (pixbase + (size_t)j * 64 + wave * 16) * CIN;
#pragma unroll
        for (int ft = 0; ft < 4; ++ft) {
#pragma unroll
            for (int r = 0; r < 4; ++r) {
                float v = a4[ft][r] + bias[ft];
                v = fmaxf(v, 0.f);
                out[obase + (size_t)(lhi * 4 + r) * CIN + ft * 16 + l16] = v;
            }
        }
    }
}

extern "C" void kernel_launch(void* const* d_in, const int* in_sizes, int n_in,
                              void* d_out, int out_size, void* d_ws, size_t ws_size,
                              hipStream_t stream) {
    (void)in_sizes; (void)n_in; (void)out_size; (void)ws_size;
    const float* t1     = (const float*)d_in[0];
    const float* t2     = (const float*)d_in[1];
    const float* t3     = (const float*)d_in[2];
    const float* w_se1  = (const float*)d_in[3];
    const float* w_se2  = (const float*)d_in[4];
    const float* w_conv = (const float*)d_in[5];
    const float* b_conv = (const float*)d_in[6];
    float* out = (float*)d_out;

    // workspace layout
    float*  partials = (float*)d_ws;                               // 512*192*4   = 393216 B
    ushort* wbT      = (ushort*)((char*)d_ws + 512 * C3 * 4);      // 8*64*192*2  = 196608 B
    ushort* xws      = (ushort*)((char*)d_ws + 1024 * 1024);       // 8*16384*192*2 = 50.3 MB

    k_prep<<<dim3(BQ * KPB), dim3(256), 0, stream>>>(t1, t2, t3, xws, partials);
    k_se  <<<dim3(BQ),       dim3(256), 0, stream>>>(partials, w_se1, w_se2, w_conv, wbT);
    k_conv<<<dim3(BQ * KPB), dim3(256), 0, stream>>>(xws, wbT, b_conv, out);
}

// Round 5
// 167.805 us; speedup vs baseline: 1.0405x; 1.0405x over previous
//
#include <hip/hip_runtime.h>
#include <hip/hip_bf16.h>

// Problem constants
#define BQ   8
#define HW   16384        // 128*128
#define CIN  64
#define C3   192
#define BPB  256          // blocks per batch (64 px per block), 2048 total

typedef __attribute__((ext_vector_type(8))) short short8;   // 8 bf16 (4 VGPR)
typedef __attribute__((ext_vector_type(4))) float f32x4;    // MFMA accumulator

__device__ __forceinline__ ushort f2bf(float f) {
    // round-to-nearest-even fp32 -> bf16 (inputs are finite normals)
    uint u = __float_as_uint(f);
    u += 0x7fffu + ((u >> 16) & 1u);
    return (ushort)(u >> 16);
}

// ---------------------------------------------------------------------------
// K1: channel sums only. 2048 blocks x 64 pixels. partials[bid][c3],
//     c3 = 3*c + t (matches SE gate indexing).
// ---------------------------------------------------------------------------
__global__ __launch_bounds__(256) void k_reduce(const float* __restrict__ t1,
                                                const float* __restrict__ t2,
                                                const float* __restrict__ t3,
                                                float* __restrict__ partials) {
    const int bid  = blockIdx.x;
    const int b    = bid >> 8;
    const int kblk = bid & 255;
    const int tid  = threadIdx.x;
    const int lane = tid & 63, wave = tid >> 6;
    const int l16  = lane & 15;

    const size_t base = ((size_t)b * HW + (size_t)kblk * 64) * CIN;
    float acc[3][4] = {{0.f,0.f,0.f,0.f},{0.f,0.f,0.f,0.f},{0.f,0.f,0.f,0.f}};
#pragma unroll
    for (int t = 0; t < 3; ++t) {
        const float* bp = (t == 0) ? t1 : (t == 1) ? t2 : t3;
        const float4* s = (const float4*)(bp + base);
#pragma unroll
        for (int i = 0; i < 2; ++i) {
            float4 v = s[i * 256 + tid];   // lane channel window (tid&15)*4 fixed
            acc[t][0] += v.x; acc[t][1] += v.y;
            acc[t][2] += v.z; acc[t][3] += v.w;
        }
    }
    // lanes l, l+16, l+32, l+48 share the same channel group -> butterfly
#pragma unroll
    for (int t = 0; t < 3; ++t)
#pragma unroll
        for (int jj = 0; jj < 4; ++jj) {
            float v = acc[t][jj];
            v += __shfl_xor(v, 16);
            v += __shfl_xor(v, 32);
            acc[t][jj] = v;
        }
    __shared__ float red[4][C3];
    if (lane < 16) {
#pragma unroll
        for (int t = 0; t < 3; ++t)
#pragma unroll
            for (int jj = 0; jj < 4; ++jj)
                red[wave][3 * (l16 * 4 + jj) + t] = acc[t][jj];
    }
    __syncthreads();
    if (tid < C3) {
        float v = red[0][tid] + red[1][tid] + red[2][tid] + red[3][tid];
        partials[(size_t)bid * C3 + tid] = v;
    }
}

// ---------------------------------------------------------------------------
// K2: finish mean, SE dense layers (fp32), emit folded bf16 weights
//     wbT[b][f][k'] with k' = t*64 + c
// ---------------------------------------------------------------------------
__global__ __launch_bounds__(256) void k_se(const float* __restrict__ partials,
                                            const float* __restrict__ w_se1,
                                            const float* __restrict__ w_se2,
                                            const float* __restrict__ w_conv,
                                            ushort* __restrict__ wbT) {
    const int b = blockIdx.x, tid = threadIdx.x;
    __shared__ float s_lds[C3];
    __shared__ float h_lds[12];
    __shared__ float sig_lds[C3];

    if (tid < C3) {
        float s = 0.f;
        const float* p = partials + (size_t)b * BPB * C3 + tid;
#pragma unroll 8
        for (int k = 0; k < BPB; ++k) s += p[k * C3];
        s_lds[tid] = s * (1.f / 16384.f);
    }
    __syncthreads();
    if (tid < 12) {
        float h = 0.f;
        for (int j = 0; j < C3; ++j) h += s_lds[j] * w_se1[j * 12 + tid];
        h_lds[tid] = fmaxf(h, 0.f);
    }
    __syncthreads();
    if (tid < C3) {
        float z = 0.f;
#pragma unroll
        for (int i = 0; i < 12; ++i) z += h_lds[i] * w_se2[i * C3 + tid];
        sig_lds[tid] = 1.f / (1.f + expf(-z));
    }
    __syncthreads();
    if (tid < C3) {
        const int c = tid & 63, t = tid >> 6;
        const int c3 = 3 * c + t;                 // original interleaved index
        const float g = sig_lds[c3];
        ushort* dst = wbT + (size_t)b * CIN * C3; // [64][192] bf16
        for (int f = 0; f < CIN; ++f)
            dst[f * C3 + tid] = f2bf(g * w_conv[c3 * CIN + f]);
    }
}

// ---------------------------------------------------------------------------
// K3: MFMA conv, A-fragments read DIRECTLY from global fp32 (L3-hot after
//     pass 1) and converted in-register. Only wt (25.6 KB) staged in LDS.
//     2048 blocks x 64 pixels, one barrier total.
// ---------------------------------------------------------------------------
__global__ __launch_bounds__(256) void k_conv(const float* __restrict__ t1,
                                              const float* __restrict__ t2,
                                              const float* __restrict__ t3,
                                              const ushort* __restrict__ wbT,
                                              const float* __restrict__ b_conv,
                                              float* __restrict__ out) {
    __shared__ ushort wt[64 * 200];   // weights [64 f][192 k'] pad->200

    const int bid  = blockIdx.x;
    const int b    = bid >> 8;
    const int kblk = bid & 255;
    const int tid  = threadIdx.x;
    const int lane = tid & 63, wave = tid >> 6;
    const int l16  = lane & 15, lhi = lane >> 4;

    // stage per-batch folded weights once
    {
        const uint2* src = (const uint2*)(wbT + (size_t)b * CIN * C3);
#pragma unroll
        for (int i = 0; i < 12; ++i) {
            int ch  = i * 256 + tid;      // 0..3071 8-byte chunks (48 per row)
            int row = ch / 48, col8 = ch % 48;
            *(uint2*)&wt[row * 200 + col8 * 4] = src[ch];
        }
    }
    float bias[4];
#pragma unroll
    for (int ft = 0; ft < 4; ++ft) bias[ft] = b_conv[ft * 16 + l16];
    __syncthreads();

    // this lane's pixel row (A-operand row = wave*16 + l16)
    const size_t pix0  = (size_t)b * HW + (size_t)kblk * 64;
    const size_t prow  = pix0 + wave * 16 + l16;

    f32x4 a4[4];
#pragma unroll
    for (int ft = 0; ft < 4; ++ft) a4[ft] = (f32x4){0.f, 0.f, 0.f, 0.f};

#pragma unroll
    for (int kt = 0; kt < 6; ++kt) {
        // k' = kt*32 + lhi*8  ->  tensor t = kt>>1, channel c0 = (kt&1)*32 + lhi*8
        const float* bp = (kt < 2) ? t1 : (kt < 4) ? t2 : t3;
        const float* src = bp + prow * CIN + (kt & 1) * 32 + lhi * 8;
        float4 v0 = *(const float4*)src;
        float4 v1 = *(const float4*)(src + 4);
        short8 a;
        a[0] = (short)f2bf(v0.x); a[1] = (short)f2bf(v0.y);
        a[2] = (short)f2bf(v0.z); a[3] = (short)f2bf(v0.w);
        a[4] = (short)f2bf(v1.x); a[5] = (short)f2bf(v1.y);
        a[6] = (short)f2bf(v1.z); a[7] = (short)f2bf(v1.w);
#pragma unroll
        for (int ft = 0; ft < 4; ++ft) {
            short8 bb = *(const short8*)&wt[(ft * 16 + l16) * 200 + kt * 32 + lhi * 8];
            a4[ft] = __builtin_amdgcn_mfma_f32_16x16x32_bf16(a, bb, a4[ft], 0, 0, 0);
        }
    }
    // D: col = l16 (f), row = lhi*4 + r (pixel)  [m89-verified layout]
    const size_t obase = (pix0 + (size_t)wave * 16) * CIN;
#pragma unroll
    for (int ft = 0; ft < 4; ++ft) {
#pragma unroll
        for (int r = 0; r < 4; ++r) {
            float v = a4[ft][r] + bias[ft];
            v = fmaxf(v, 0.f);
            out[obase + (size_t)(lhi * 4 + r) * CIN + ft * 16 + l16] = v;
        }
    }
}

extern "C" void kernel_launch(void* const* d_in, const int* in_sizes, int n_in,
                              void* d_out, int out_size, void* d_ws, size_t ws_size,
                              hipStream_t stream) {
    (void)in_sizes; (void)n_in; (void)out_size; (void)ws_size;
    const float* t1     = (const float*)d_in[0];
    const float* t2     = (const float*)d_in[1];
    const float* t3     = (const float*)d_in[2];
    const float* w_se1  = (const float*)d_in[3];
    const float* w_se2  = (const float*)d_in[4];
    const float* w_conv = (const float*)d_in[5];
    const float* b_conv = (const float*)d_in[6];
    float* out = (float*)d_out;

    float*  partials = (float*)d_ws;                                 // 2048*192*4 = 1.57 MB
    ushort* wbT      = (ushort*)((char*)d_ws + 2048 * C3 * 4);       // 8*64*192*2 = 196608 B

    k_reduce<<<dim3(BQ * BPB), dim3(256), 0, stream>>>(t1, t2, t3, partials);
    k_se    <<<dim3(BQ),       dim3(256), 0, stream>>>(partials, w_se1, w_se2, w_conv, wbT);
    k_conv  <<<dim3(BQ * BPB), dim3(256), 0, stream>>>(t1, t2, t3, wbT, b_conv, out);
}